// Round 15
// baseline (807.239 us; speedup 1.0000x reference)
//
#include <hip/hip_runtime.h>
#include <cstdint>

#define K_IN   4096
#define N_OUT  4096
#define M_ROWS 16384
#define RANK   8
#define LSCALE 1.0f    // alpha/rank = 8/8
#define NT     64      // K_IN / 64  (BK=64 K-tiles)
#define ROWB   8192    // K_IN * 2 bytes per global row
#define AHALF  1048576 // 128 rows * ROWB

typedef __attribute__((ext_vector_type(8))) short  short8;
typedef __attribute__((ext_vector_type(4))) float  floatx4;

__device__ __forceinline__ unsigned short f2bf(float f) {
  uint32_t u = __float_as_uint(f);
  u += 0x7FFFu + ((u >> 16) & 1u);
  return (unsigned short)(u >> 16);
}

__global__ __launch_bounds__(256) void fold_w_kernel(
    const float* __restrict__ W, const float* __restrict__ lA,
    const float* __restrict__ lB, unsigned short* __restrict__ Weff) {
  int idx = blockIdx.x * 256 + threadIdx.x;
  int o = idx >> 10;
  int k = (idx & 1023) << 2;
  float4 w = *reinterpret_cast<const float4*>(W + (size_t)o * K_IN + k);
#pragma unroll
  for (int r = 0; r < RANK; ++r) {
    float s = LSCALE * lB[o * RANK + r];
    float4 a = *reinterpret_cast<const float4*>(lA + r * K_IN + k);
    w.x += s * a.x; w.y += s * a.y; w.z += s * a.z; w.w += s * a.w;
  }
  ushort4 p;
  p.x = f2bf(w.x); p.y = f2bf(w.y); p.z = f2bf(w.z); p.w = f2bf(w.w);
  *reinterpret_cast<ushort4*>(Weff + (size_t)o * K_IN + k) = p;
}

__global__ __launch_bounds__(256) void cvt_x_kernel(
    const float* __restrict__ x, unsigned short* __restrict__ xb) {
  size_t i = ((size_t)blockIdx.x * 256 + threadIdx.x) * 8;
  float4 a = *reinterpret_cast<const float4*>(x + i);
  float4 c = *reinterpret_cast<const float4*>(x + i + 4);
  uint4 v;
  v.x = (uint32_t)f2bf(a.x) | ((uint32_t)f2bf(a.y) << 16);
  v.y = (uint32_t)f2bf(a.z) | ((uint32_t)f2bf(a.w) << 16);
  v.z = (uint32_t)f2bf(c.x) | ((uint32_t)f2bf(c.y) << 16);
  v.w = (uint32_t)f2bf(c.z) | ((uint32_t)f2bf(c.w) << 16);
  *reinterpret_cast<uint4*>(xb + i) = v;
}

__device__ __forceinline__ void gload_lds16(const void* g, void* l) {
  __builtin_amdgcn_global_load_lds(
      (const __attribute__((address_space(1))) void*)g,
      (__attribute__((address_space(3))) void*)l, 16, 0, 0);
}

#define BAR() do { asm volatile("" ::: "memory");                         \
    __builtin_amdgcn_s_barrier();                                         \
    asm volatile("" ::: "memory"); } while (0)

#define DSR(DST, ADDR, IMM)                                               \
  asm volatile("ds_read_b128 %0, %1 offset:%2"                            \
               : "=v"(DST) : "v"(ADDR), "i"(IMM))
// counted waits + sched_barrier (rule 18 — asm-loaded regs need the fence)
#define LGKM(N) do {                                                      \
    asm volatile("s_waitcnt lgkmcnt(" #N ")" ::: "memory");               \
    __builtin_amdgcn_sched_barrier(0); } while (0)
#define VMW(N) do {                                                       \
    asm volatile("s_waitcnt vmcnt(" #N ")" ::: "memory");                 \
    __builtin_amdgcn_sched_barrier(0); } while (0)
// B direct-to-register load: SGPR base + 32-bit per-lane voffset + imm
#define GLB(DST, VOFF, IMM)                                               \
  asm volatile("global_load_dwordx4 %0, %1, %2 offset:%3"                 \
               : "=v"(DST) : "v"(VOFF), "s"(Wb), "i"(IMM))

// ---------------------------------------------------------------------------
// R15: B NEVER TOUCHES LDS. R12-R14 showed the LDS pipe (192 reads x12cyc +
// 64KB DMA writes ~ 2800 cyc/tile/CU) oversubscribed vs MFMA (2483): no
// schedule could hide it (R12 489us/53% was the best permutation). B frags
// now load straight from Weff to regs (each lane's 16B IS its operand; the
// LDS swizzle round-trip was data-identity). LDS: A only (2x32KB dbuf),
// reads 16/wave/tile (1536 cyc), writes 32KB -> both < MFMA => hideable.
// XCD map flipped to nt-SLOW (nt=sbx>>6): 128 co-running blocks per XCD
// share 2 nt values -> B working set 4MB/XCD = L2 size (B must be L2-hot
// since it's now on the latency-sensitive VMEM path; A keeps the
// latency-tolerant DMA path).
// Phases (R12 4-barrier skeleton), steady state tile t:
//  P0: DSR afB(t)8; STAGE A(t+1) 4 gloads; LGKM(8)[afA]; VMW(8)[bfC(t);
//      queue bfC4,bfD4,Ast4=12]; MFMA(0,0)[afA,bfC]; BAR
//  P1: VMW(4)[bfD(t); Ast outstanding]; MFMA(0,1)[afA,bfD]; BAR
//  P2: LGKM(0)[afB]; MFMA(1,0)[afB,bfC]; vb+=128; GLB bfC(t+1)4;
//      VMW(4)[Ast(t+1) done, bfC' in flight]; BAR  <- cert rendezvous
//  P3: aCur^=32768; DSR afA(t+1)8; MFMA(1,1)[afB,bfD]; GLB bfD(t+1)4; BAR
// vmcnt ledger (in-order; entering P0(t): [bfC(t)4, bfD(t)4]): P0 +Ast4
// ->12, VMW(8)=bfC; P1 VMW(4)=bfD; P2 +bfC'4 after VMW... bfC' issued
// BEFORE VMW(4): queue [Ast4,bfC'4] -> VMW(4) retires Ast exactly. P3 +bfD'.
// lgkm ledger: [afA8(P3 prev), afB8(P0)]: LGKM(8)=afA; LGKM(0)@P2=afB.
// WAR: buf-t reads (afB issued P0(t)) retired by LGKM(0)@P2(t) + BAR;
// Ast(t+2) issues at P0(t+1) after that BAR -> safe. Cert: every wave's
// VMW(4)@P2 retires its Ast(t+1); BAR rendezvous before P3's reads -> safe.
// Tail t=NT-1: no stage (VMW(4)@P0, VMW(0)@P1), no bfC'/cert@P2, no
// toggle/reads/bfD'@P3. B reg WAR (loads overwrite just-consumed frags)
// is SSA-explicit; vmcnt order pinned: all VMEM ops are side-effecting
// (asm volatile / gload_lds builtin) so issue order is program order.
// ---------------------------------------------------------------------------
__global__ __launch_bounds__(512, 2) void gemm256_kernel(
    const unsigned short* __restrict__ Xb, const unsigned short* __restrict__ Wb,
    const float* __restrict__ bias, float* __restrict__ out) {
  __shared__ alignas(16) char lds[2 * 32768];   // 64 KiB, A only

  const int tid  = threadIdx.x;
  const int wave = tid >> 6, lane = tid & 63;
  const int wr = wave >> 2, wc = wave & 3;      // 2 (M) x 4 (N) wave grid
  const int l15 = lane & 15, sq = lane >> 4;

  // XCD swizzle, nt-SLOW: per-XCD chunk = 2 nt x 64 mt -> B L2-resident
  int bx  = blockIdx.x;
  int sbx = (bx & 7) * 128 + (bx >> 3);
  const int nt = sbx >> 6;   // 0..15  (slow: 2 per XCD chunk)
  const int mt = sbx & 63;   // 0..63

  // A staging source pre-swizzle (proven R9/R11)
  const int rstg = tid >> 3;
  const int cbst = (((tid & 7) ^ ((tid >> 3) & 7)) << 4);
  const char* aBase = (const char*)Xb + (size_t)(mt * 256 + rstg) * ROWB + cbst;

#define STAGE_A(TH) do {                                                  \
    const char* s0_ = aBase + (TH) * 128;                                 \
    char* d0_ = lds + ((TH) & 1) * 32768 + tid * 16;                      \
    gload_lds16(s0_, d0_);                                                \
    gload_lds16(s0_ + (size_t)64 * ROWB, d0_ + 8192);                     \
    const char* s1_ = s0_ + AHALF;                                        \
    gload_lds16(s1_, d0_ + 16384);                                        \
    gload_lds16(s1_ + (size_t)64 * ROWB, d0_ + 24576);                    \
  } while (0)

  // A LDS read bases (R11 carry-free form; half = wr at offset wr*16384)
  const unsigned ldsb = (unsigned)(unsigned long long)
      (__attribute__((address_space(3))) char*)lds;
  const unsigned X = (unsigned)((l15 & 7) << 4);
  const unsigned aRow = ldsb + wr * 16384 + l15 * 128;
  unsigned aCur0 = aRow + ((0u  + sq * 16) ^ X);
  unsigned aCur1 = aRow + ((64u + sq * 16) ^ X);

  // B per-lane voffsets: row = nt*256 + wc*64 + nq*32 + fj*16 + l15
  unsigned vb00 = (unsigned)(nt * 256 + wc * 64 + l15) * ROWB + sq * 16;
  unsigned vb01 = vb00 + 16u * ROWB;
  unsigned vb10 = vb00 + 32u * ROWB;
  unsigned vb11 = vb00 + 48u * ROWB;

#define LOAD_A(DST, MQ) do {                                              \
    _Pragma("unroll")                                                     \
    for (int fi = 0; fi < 4; ++fi)                                        \
      DSR(DST[fi],     aCur0, (MQ) * 8192 + fi * 2048);                   \
    _Pragma("unroll")                                                     \
    for (int fi = 0; fi < 4; ++fi)                                        \
      DSR(DST[4 + fi], aCur1, (MQ) * 8192 + fi * 2048);                   \
  } while (0)
  // B frag DST[ks*2+fj]: voff(nq,fj) + ks*64 imm
#define LOAD_BC() do { GLB(bfC[0], vb00, 0); GLB(bfC[1], vb01, 0);        \
    GLB(bfC[2], vb00, 64); GLB(bfC[3], vb01, 64); } while (0)
#define LOAD_BD() do { GLB(bfD[0], vb10, 0); GLB(bfD[1], vb11, 0);        \
    GLB(bfD[2], vb10, 64); GLB(bfD[3], vb11, 64); } while (0)
#define MFMA_Q(MQ, NQ, AF, BF) do {                                       \
    __builtin_amdgcn_s_setprio(1);                                        \
    _Pragma("unroll")                                                     \
    for (int ks = 0; ks < 2; ++ks)                                        \
      _Pragma("unroll")                                                   \
      for (int fi = 0; fi < 4; ++fi)                                      \
        _Pragma("unroll")                                                 \
        for (int fj = 0; fj < 2; ++fj)                                    \
          acc[(MQ) * 4 + fi][(NQ) * 2 + fj] =                             \
              __builtin_amdgcn_mfma_f32_16x16x32_bf16(                    \
                  AF[ks * 4 + fi], BF[ks * 2 + fj],                       \
                  acc[(MQ) * 4 + fi][(NQ) * 2 + fj], 0, 0, 0);            \
    __builtin_amdgcn_s_setprio(0); } while (0)

  floatx4 acc[8][4];
#pragma unroll
  for (int i = 0; i < 8; ++i)
#pragma unroll
    for (int j = 0; j < 4; ++j)
      acc[i][j] = (floatx4){0.f, 0.f, 0.f, 0.f};

  short8 afA[8], afB[8], bfC[4], bfD[4];

  // prologue: stage A(0) [4 gloads]; B(0) [8 loads]; vmcnt(8) retires A(0);
  // BAR; preload afA(0)
  STAGE_A(0);
  LOAD_BC();
  LOAD_BD();
  VMW(8);
  BAR();
  LOAD_A(afA, 0);

  for (int t = 0; t < NT; ++t) {
    // ---- P0
    LOAD_A(afB, 1);                 // lgkm queue: [afA8, afB8]
    if (t <= NT - 2) { STAGE_A(t + 1); }
    LGKM(8);                        // afA landed
    if (t <= NT - 2) VMW(8); else VMW(4);   // bfC(t) landed
    MFMA_Q(0, 0, afA, bfC);
    BAR();

    // ---- P1
    if (t <= NT - 2) VMW(4); else VMW(0);   // bfD(t) landed
    MFMA_Q(0, 1, afA, bfD);
    BAR();

    // ---- P2
    LGKM(0);                        // afB landed
    MFMA_Q(1, 0, afB, bfC);
    if (t <= NT - 2) {
      vb00 += 128; vb01 += 128; vb10 += 128; vb11 += 128;
      LOAD_BC();                    // bfC(t+1); queue [Ast4, bfC'4]
      VMW(4);                       // Ast(t+1) retired; bfC' in flight
    }
    BAR();                          // cert rendezvous for buf (t+1)&1

    // ---- P3
    if (t <= NT - 2) {
      aCur0 ^= 32768u; aCur1 ^= 32768u;
      LOAD_A(afA, 0);               // afA(t+1) from certified buf
    }
    MFMA_Q(1, 1, afB, bfD);
    if (t <= NT - 2) LOAD_BD();     // bfD(t+1)
    BAR();
  }
#undef STAGE_A
#undef LOAD_A
#undef LOAD_BC
#undef LOAD_BD
#undef MFMA_Q

  // epilogue: C/D layout col=lane&15, row=(lane>>4)*4+reg (m89/m91 verified)
  const int row0 = mt * 256 + wr * 128 + sq * 4;
  const int col0 = nt * 256 + wc * 64 + l15;
#pragma unroll
  for (int j = 0; j < 4; ++j) {
    int col = col0 + j * 16;
    float bv = bias[col];
#pragma unroll
    for (int i = 0; i < 8; ++i) {
      int rowb = row0 + i * 16;
#pragma unroll
      for (int rr = 0; rr < 4; ++rr)
        out[(size_t)(rowb + rr) * N_OUT + col] = acc[i][j][rr] + bv;
    }
  }
}

// self-contained correct fallback (only if ws too small): tiled fp32
__global__ __launch_bounds__(256) void fallback_kernel(
    const float* __restrict__ x, const float* __restrict__ W,
    const float* __restrict__ bias, const float* __restrict__ lA,
    const float* __restrict__ lB, float* __restrict__ out) {
  __shared__ float Xs[64][17];
  __shared__ float Ws[64][17];
  int tid = threadIdx.x;
  int tx = tid & 15, ty = tid >> 4;
  int bm = blockIdx.y * 64, bn = blockIdx.x * 64;
  float acc[4][4] = {};
  for (int k0 = 0; k0 < K_IN; k0 += 16) {
#pragma unroll
    for (int q = 0; q < 4; ++q) {
      int flat = q * 256 + tid;
      int r = flat >> 4, c = flat & 15;
      Xs[r][c] = x[(size_t)(bm + r) * K_IN + k0 + c];
      float w = W[(size_t)(bn + r) * K_IN + k0 + c];
#pragma unroll
      for (int rr = 0; rr < RANK; ++rr)
        w += LSCALE * lB[(bn + r) * RANK + rr] * lA[rr * K_IN + k0 + c];
      Ws[r][c] = w;
    }
    __syncthreads();
#pragma unroll
    for (int kk = 0; kk < 16; ++kk) {
      float av[4], bv[4];
#pragma unroll
      for (int i = 0; i < 4; ++i) av[i] = Xs[ty * 4 + i][kk];
#pragma unroll
      for (int j = 0; j < 4; ++j) bv[j] = Ws[tx * 4 + j][kk];
#pragma unroll
      for (int i = 0; i < 4; ++i)
#pragma unroll
        for (int j = 0; j < 4; ++j) acc[i][j] += av[i] * bv[j];
    }
    __syncthreads();
  }
#pragma unroll
  for (int i = 0; i < 4; ++i)
#pragma unroll
    for (int j = 0; j < 4; ++j)
      out[(size_t)(bm + ty * 4 + i) * N_OUT + bn + tx * 4 + j] =
          acc[i][j] + bias[bn + tx * 4 + j];
}

extern "C" void kernel_launch(void* const* d_in, const int* in_sizes, int n_in,
                              void* d_out, int out_size, void* d_ws, size_t ws_size,
                              hipStream_t stream) {
  const float* x  = (const float*)d_in[0];
  const float* W  = (const float*)d_in[1];
  const float* b  = (const float*)d_in[2];
  const float* lA = (const float*)d_in[3];
  const float* lB = (const float*)d_in[4];
  float* out = (float*)d_out;

  const size_t weff_bytes = (size_t)N_OUT * K_IN * 2;    // 32 MB
  const size_t xb_bytes   = (size_t)M_ROWS * K_IN * 2;   // 128 MB

  if (ws_size >= weff_bytes + xb_bytes) {
    unsigned short* Weff = (unsigned short*)d_ws;
    unsigned short* Xb   = (unsigned short*)((char*)d_ws + weff_bytes);
    fold_w_kernel<<<(int)(((size_t)N_OUT * K_IN / 4) / 256), 256, 0, stream>>>(W, lA, lB, Weff);
    cvt_x_kernel<<<(int)(((size_t)M_ROWS * K_IN / 8) / 256), 256, 0, stream>>>(x, Xb);
    gemm256_kernel<<<(M_ROWS / 256) * (N_OUT / 256), 512, 0, stream>>>(Xb, Weff, b, out);
  } else {
    dim3 grid(N_OUT / 64, M_ROWS / 64);
    fallback_kernel<<<grid, 256, 0, stream>>>(x, W, b, lA, lB, out);
  }
}

// Round 16
// 572.579 us; speedup vs baseline: 1.4098x; 1.4098x over previous
//
#include <hip/hip_runtime.h>
#include <cstdint>

#define K_IN   4096
#define N_OUT  4096
#define M_ROWS 16384
#define RANK   8
#define LSCALE 1.0f    // alpha/rank = 8/8
#define NT     64      // K_IN / 64  (BK=64 K-tiles)
#define ROWB   8192    // K_IN * 2 bytes per global row
#define AHALF  1048576 // 128 rows * ROWB

typedef __attribute__((ext_vector_type(8))) short  short8;
typedef __attribute__((ext_vector_type(4))) float  floatx4;

__device__ __forceinline__ unsigned short f2bf(float f) {
  uint32_t u = __float_as_uint(f);
  u += 0x7FFFu + ((u >> 16) & 1u);
  return (unsigned short)(u >> 16);
}

__global__ __launch_bounds__(256) void fold_w_kernel(
    const float* __restrict__ W, const float* __restrict__ lA,
    const float* __restrict__ lB, unsigned short* __restrict__ Weff) {
  int idx = blockIdx.x * 256 + threadIdx.x;
  int o = idx >> 10;
  int k = (idx & 1023) << 2;
  float4 w = *reinterpret_cast<const float4*>(W + (size_t)o * K_IN + k);
#pragma unroll
  for (int r = 0; r < RANK; ++r) {
    float s = LSCALE * lB[o * RANK + r];
    float4 a = *reinterpret_cast<const float4*>(lA + r * K_IN + k);
    w.x += s * a.x; w.y += s * a.y; w.z += s * a.z; w.w += s * a.w;
  }
  ushort4 p;
  p.x = f2bf(w.x); p.y = f2bf(w.y); p.z = f2bf(w.z); p.w = f2bf(w.w);
  *reinterpret_cast<ushort4*>(Weff + (size_t)o * K_IN + k) = p;
}

__global__ __launch_bounds__(256) void cvt_x_kernel(
    const float* __restrict__ x, unsigned short* __restrict__ xb) {
  size_t i = ((size_t)blockIdx.x * 256 + threadIdx.x) * 8;
  float4 a = *reinterpret_cast<const float4*>(x + i);
  float4 c = *reinterpret_cast<const float4*>(x + i + 4);
  uint4 v;
  v.x = (uint32_t)f2bf(a.x) | ((uint32_t)f2bf(a.y) << 16);
  v.y = (uint32_t)f2bf(a.z) | ((uint32_t)f2bf(a.w) << 16);
  v.z = (uint32_t)f2bf(c.x) | ((uint32_t)f2bf(c.y) << 16);
  v.w = (uint32_t)f2bf(c.z) | ((uint32_t)f2bf(c.w) << 16);
  *reinterpret_cast<uint4*>(xb + i) = v;
}

__device__ __forceinline__ void gload_lds16(const void* g, void* l) {
  __builtin_amdgcn_global_load_lds(
      (const __attribute__((address_space(1))) void*)g,
      (__attribute__((address_space(3))) void*)l, 16, 0, 0);
}

#define BAR() do { asm volatile("" ::: "memory");                         \
    __builtin_amdgcn_s_barrier();                                         \
    asm volatile("" ::: "memory"); } while (0)

#define DSR(DST, ADDR, IMM)                                               \
  asm volatile("ds_read_b128 %0, %1 offset:%2"                            \
               : "=v"(DST) : "v"(ADDR), "i"(IMM))
#define LGKM(N) do {                                                      \
    asm volatile("s_waitcnt lgkmcnt(" #N ")" ::: "memory");               \
    __builtin_amdgcn_sched_barrier(0); } while (0)
#define VMW(N) do {                                                       \
    asm volatile("s_waitcnt vmcnt(" #N ")" ::: "memory");                 \
    __builtin_amdgcn_sched_barrier(0); } while (0)

// ---------------------------------------------------------------------------
// R16 = R12 (best: 489us, MfmaUtil 53) + NEVER-DRAIN STAGING.
// R12's one remaining template violation: vmcnt(0) at P2 (full drain) and a
// 3-half stage burst at P3. m201's rule: counted vmcnt only, 1 half/phase.
// Stage schedule: P0: h3(t+1); P1: h0(t+2); P2: h1(t+2); P3: h2(t+2).
// Cert: VMW(4) at P2 AFTER staging h1(t+2) — queue (in-order) is
// [h3(t+1)2, h0(t+2)2, h1(t+2)2]=6, so VMW(4) retires exactly h3(t+1)
// => tile t+1 fully landed, 4 loads stay in flight (never 0 mid-loop).
// Reads (identical to R12): P3 issues afA/bfC(t+1); P0 issues bfD/afB(t);
// counted LGKM(12)/(8)/(0) at P0/P1/P2.
// lgkm FIFO at P0(t) entry: [afA8,bfC4] + issue [bfD4,afB8] = 24:
//   LGKM(12)->afA+bfC; P1 LGKM(8)->bfD; P2 LGKM(0)->afB.
// vmcnt ledger t=0: prologue stages h0..h3(0),h0,h1,h2(1) [14 loads],
//   VMW(6) retires tile 0, leaves [h0h1h2(1)]=6. P0(0) +h3(1);
//   P1(0)+h0(2); P2(0)+h1(2) -> VMW(4) retires through h3(1). OK
// Tails: P0 stage t<=NT-2; P1/P2/P3 stages t<=NT-3;
//   P2 cert: t<=NT-3 -> VMW(4); t==NT-2 -> VMW(0) (only h3(NT-1) out,
//   2-phase lead ~1200cyc, same as R12 had every tile); t==NT-1 skip.
//   P3 reads t<=NT-2.
// WAR (R8-pattern, 6x validated): stage h(t+2) into buf t&1 at P1/P2/P3
// while the last buf-t ds_reads (afB, issued P0(t)) are >=1 barrier +
// DS-queue ahead of the DMA's L2/HBM round trip; own-wave retired by
// LGKM(0)@P2. Swizzle LDSWZ2 (R9: conflicts=0.0), R11 carry-free bases.
// ---------------------------------------------------------------------------
__global__ __launch_bounds__(512, 2) void gemm256_kernel(
    const unsigned short* __restrict__ Xb, const unsigned short* __restrict__ Wb,
    const float* __restrict__ bias, float* __restrict__ out) {
  __shared__ alignas(16) char lds[2 * 65536];   // 128 KiB

  const int tid  = threadIdx.x;
  const int wave = tid >> 6, lane = tid & 63;
  const int wr = wave >> 2, wc = wave & 3;      // 2 (M) x 4 (N) wave grid
  const int l15 = lane & 15, sq = lane >> 4;

  // XCD swizzle: 1024 blocks (%8==0), contiguous 128-tile chunk per XCD
  int bx  = blockIdx.x;
  int sbx = (bx & 7) * 128 + (bx >> 3);
  const int mt = sbx >> 4;   // 0..63
  const int nt = sbx & 15;   // 0..15

  // staging source pre-swizzle (proven R9/R11)
  const int rstg = tid >> 3;
  const int cbst = (((tid & 7) ^ ((tid >> 3) & 7)) << 4);
  const char* aBase = (const char*)Xb + (size_t)(mt * 256 + rstg) * ROWB + cbst;
  const char* bBase = (const char*)Wb + (size_t)(nt * 256 + rstg) * ROWB + cbst;

#define STAGE_TH(TH, HH) do {                                             \
    const char* src_ = ((HH) < 2 ? aBase + (size_t)(HH) * AHALF           \
                                 : bBase + (size_t)((HH) - 2) * AHALF)    \
                       + (TH) * 128;                                      \
    char* dst_ = lds + ((TH) & 1) * 65536 + (HH) * 16384 + tid * 16;      \
    gload_lds16(src_, dst_);                                              \
    gload_lds16(src_ + (size_t)64 * ROWB, dst_ + 8192);                   \
  } while (0)

  // LDS read bases (R11: ks folded inside XOR; imms pure row terms)
  const unsigned ldsb = (unsigned)(unsigned long long)
      (__attribute__((address_space(3))) char*)lds;
  const unsigned X = (unsigned)((l15 & 7) << 4);
  const unsigned aRow = ldsb + wr * 16384 + l15 * 128;
  const unsigned bRow = ldsb + (2 + (wc >> 1)) * 16384 + (wc & 1) * 8192
                        + l15 * 128;
  unsigned aCur0 = aRow + ((0u  + sq * 16) ^ X);
  unsigned aCur1 = aRow + ((64u + sq * 16) ^ X);
  unsigned bCur0 = bRow + ((0u  + sq * 16) ^ X);
  unsigned bCur1 = bRow + ((64u + sq * 16) ^ X);

#define LOAD_A(DST, MQ) do {                                              \
    _Pragma("unroll")                                                     \
    for (int fi = 0; fi < 4; ++fi)                                        \
      DSR(DST[fi],     aCur0, (MQ) * 8192 + fi * 2048);                   \
    _Pragma("unroll")                                                     \
    for (int fi = 0; fi < 4; ++fi)                                        \
      DSR(DST[4 + fi], aCur1, (MQ) * 8192 + fi * 2048);                   \
  } while (0)
#define LOAD_B4(DST, NQ) do {                                             \
    DSR(DST[0], bCur0, (NQ) * 4096);                                      \
    DSR(DST[1], bCur0, (NQ) * 4096 + 2048);                               \
    DSR(DST[2], bCur1, (NQ) * 4096);                                      \
    DSR(DST[3], bCur1, (NQ) * 4096 + 2048);                               \
  } while (0)
#define MFMA_Q(MQ, NQ, AF, BF) do {                                       \
    __builtin_amdgcn_s_setprio(1);                                        \
    _Pragma("unroll")                                                     \
    for (int ks = 0; ks < 2; ++ks)                                        \
      _Pragma("unroll")                                                   \
      for (int fi = 0; fi < 4; ++fi)                                      \
        _Pragma("unroll")                                                 \
        for (int fj = 0; fj < 2; ++fj)                                    \
          acc[(MQ) * 4 + fi][(NQ) * 2 + fj] =                             \
              __builtin_amdgcn_mfma_f32_16x16x32_bf16(                    \
                  AF[ks * 4 + fi], BF[ks * 2 + fj],                       \
                  acc[(MQ) * 4 + fi][(NQ) * 2 + fj], 0, 0, 0);            \
    __builtin_amdgcn_s_setprio(0); } while (0)

  floatx4 acc[8][4];
#pragma unroll
  for (int i = 0; i < 8; ++i)
#pragma unroll
    for (int j = 0; j < 4; ++j)
      acc[i][j] = (floatx4){0.f, 0.f, 0.f, 0.f};

  // prologue: tile0 (4 halves) + tile1 h0,h1,h2 = 14 loads; VMW(6) retires
  // tile0 leaving 6 in flight; preload afA(0), bfC(0)
  STAGE_TH(0, 0); STAGE_TH(0, 1); STAGE_TH(0, 2); STAGE_TH(0, 3);
  STAGE_TH(1, 0); STAGE_TH(1, 1); STAGE_TH(1, 2);
  VMW(6);
  BAR();

  short8 afA[8], afB[8], bfC[4], bfD[4];
  LOAD_A(afA, 0);
  LOAD_B4(bfC, 0);

  for (int t = 0; t < NT; ++t) {
    // ---- P0: issue bfD(t), afB(t); stage h3(t+1); MFMA(0,0)
    LOAD_B4(bfD, 1);
    LOAD_A(afB, 1);
    if (t <= NT - 2) STAGE_TH(t + 1, 3);
    LGKM(12);                       // afA + bfC landed
    MFMA_Q(0, 0, afA, bfC);
    BAR();

    // ---- P1: stage h0(t+2); MFMA(0,1)
    if (t <= NT - 3) STAGE_TH(t + 2, 0);
    LGKM(8);                        // bfD landed
    MFMA_Q(0, 1, afA, bfD);
    BAR();

    // ---- P2: stage h1(t+2); MFMA(1,0); counted cert of tile t+1
    if (t <= NT - 3) STAGE_TH(t + 2, 1);
    LGKM(0);                        // afB landed
    MFMA_Q(1, 0, afB, bfC);
    if (t <= NT - 3)      VMW(4);   // retires h3(t+1) exactly; 4 in flight
    else if (t == NT - 2) VMW(0);   // tail: only h3(NT-1) outstanding
    BAR();                          // buf (t+1)&1 certified for all waves

    // ---- P3: issue afA/bfC(t+1); stage h2(t+2); MFMA(1,1)
    if (t <= NT - 2) {
      aCur0 ^= 65536u; aCur1 ^= 65536u; bCur0 ^= 65536u; bCur1 ^= 65536u;
      LOAD_A(afA, 0);
      LOAD_B4(bfC, 0);
    }
    if (t <= NT - 3) STAGE_TH(t + 2, 2);
    __builtin_amdgcn_sched_barrier(0);
    MFMA_Q(1, 1, afB, bfD);
    BAR();
  }
#undef STAGE_TH
#undef LOAD_A
#undef LOAD_B4
#undef MFMA_Q

  // epilogue: C/D layout col=lane&15, row=(lane>>4)*4+reg (m89/m91 verified)
  const int row0 = mt * 256 + wr * 128 + sq * 4;
  const int col0 = nt * 256 + wc * 64 + l15;
#pragma unroll
  for (int j = 0; j < 4; ++j) {
    int col = col0 + j * 16;
    float bv = bias[col];
#pragma unroll
    for (int i = 0; i < 8; ++i) {
      int rowb = row0 + i * 16;
#pragma unroll
      for (int rr = 0; rr < 4; ++rr)
        out[(size_t)(rowb + rr) * N_OUT + col] = acc[i][j][rr] + bv;
    }
  }
}

// self-contained correct fallback (only if ws too small): tiled fp32
__global__ __launch_bounds__(256) void fallback_kernel(
    const float* __restrict__ x, const float* __restrict__ W,
    const float* __restrict__ bias, const float* __restrict__ lA,
    const float* __restrict__ lB, float* __restrict__ out) {
  __shared__ float Xs[64][17];
  __shared__ float Ws[64][17];
  int tid = threadIdx.x;
  int tx = tid & 15, ty = tid >> 4;
  int bm = blockIdx.y * 64, bn = blockIdx.x * 64;
  float acc[4][4] = {};
  for (int k0 = 0; k0 < K_IN; k0 += 16) {
#pragma unroll
    for (int q = 0; q < 4; ++q) {
      int flat = q * 256 + tid;
      int r = flat >> 4, c = flat & 15;
      Xs[r][c] = x[(size_t)(bm + r) * K_IN + k0 + c];
      float w = W[(size_t)(bn + r) * K_IN + k0 + c];
#pragma unroll
      for (int rr = 0; rr < RANK; ++rr)
        w += LSCALE * lB[(bn + r) * RANK + rr] * lA[rr * K_IN + k0 + c];
      Ws[r][c] = w;
    }
    __syncthreads();
#pragma unroll
    for (int kk = 0; kk < 16; ++kk) {
      float av[4], bv[4];
#pragma unroll
      for (int i = 0; i < 4; ++i) av[i] = Xs[ty * 4 + i][kk];
#pragma unroll
      for (int j = 0; j < 4; ++j) bv[j] = Ws[tx * 4 + j][kk];
#pragma unroll
      for (int i = 0; i < 4; ++i)
#pragma unroll
        for (int j = 0; j < 4; ++j) acc[i][j] += av[i] * bv[j];
    }
    __syncthreads();
  }
#pragma unroll
  for (int i = 0; i < 4; ++i)
#pragma unroll
    for (int j = 0; j < 4; ++j)
      out[(size_t)(bm + ty * 4 + i) * N_OUT + bn + tx * 4 + j] =
          acc[i][j] + bias[bn + tx * 4 + j];
}

extern "C" void kernel_launch(void* const* d_in, const int* in_sizes, int n_in,
                              void* d_out, int out_size, void* d_ws, size_t ws_size,
                              hipStream_t stream) {
  const float* x  = (const float*)d_in[0];
  const float* W  = (const float*)d_in[1];
  const float* b  = (const float*)d_in[2];
  const float* lA = (const float*)d_in[3];
  const float* lB = (const float*)d_in[4];
  float* out = (float*)d_out;

  const size_t weff_bytes = (size_t)N_OUT * K_IN * 2;    // 32 MB
  const size_t xb_bytes   = (size_t)M_ROWS * K_IN * 2;   // 128 MB

  if (ws_size >= weff_bytes + xb_bytes) {
    unsigned short* Weff = (unsigned short*)d_ws;
    unsigned short* Xb   = (unsigned short*)((char*)d_ws + weff_bytes);
    fold_w_kernel<<<(int)(((size_t)N_OUT * K_IN / 4) / 256), 256, 0, stream>>>(W, lA, lB, Weff);
    cvt_x_kernel<<<(int)(((size_t)M_ROWS * K_IN / 8) / 256), 256, 0, stream>>>(x, Xb);
    gemm256_kernel<<<(M_ROWS / 256) * (N_OUT / 256), 512, 0, stream>>>(Xb, Weff, b, out);
  } else {
    dim3 grid(N_OUT / 64, M_ROWS / 64);
    fallback_kernel<<<grid, 256, 0, stream>>>(x, W, b, lA, lB, out);
  }
}